// Round 1
// baseline (304.855 us; speedup 1.0000x reference)
//
#include <hip/hip_runtime.h>

// Conv1d: x (32, 64, 16384) f32, w (64, 64, 3) f32, bias (64) f32
// -> out (32, 64, 16382) f32, VALID, stride 1.
// GEMM view: out[co][n] = sum_k A[co][k] * Bm[k][n] + bias[co]
//   k = ci*3 + kk (natural weight order, so A-frags are 8 contiguous bf16)
//   Bm[k][n] = x[b][ci][l0 + n + kk]  (implicit im2col from LDS tile)

typedef __bf16 bf16x8 __attribute__((ext_vector_type(8)));
typedef unsigned short ushort8 __attribute__((ext_vector_type(8)));
typedef float f32x16 __attribute__((ext_vector_type(16)));

#define C_IN 64
#define C_OUT 64
#define L_IN 16384
#define L_OUT 16382
#define NT 256          // n-columns per block
#define PX 264          // xs row pitch (elems)  [258 needed + pad]
#define PW 200          // wl row pitch (elems)  [192 needed + pad, keeps 16B align]

__device__ __forceinline__ unsigned short f2bf(float f) {
  unsigned u = __builtin_bit_cast(unsigned, f);
  return (unsigned short)((u + 0x7FFFu + ((u >> 16) & 1u)) >> 16);  // RNE
}

__global__ __launch_bounds__(256, 2) void conv1d_mfma(
    const float* __restrict__ x, const float* __restrict__ w,
    const float* __restrict__ bias, float* __restrict__ out) {
  __shared__ __align__(16) unsigned short xs[C_IN * PX];   // 33792 B
  __shared__ __align__(16) unsigned short wl[C_OUT * PW];  // 25600 B
  __shared__ float bias_s[C_OUT];

  const int t = threadIdx.x;
  const int bx = blockIdx.x;
  const int b = bx >> 6;        // batch
  const int tile = bx & 63;     // l-tile
  const int l0 = tile * NT;

  // ---- weights -> LDS bf16, layout wl[co][ci*3+kk], pitch PW (coalesced read)
  for (int i = t; i < C_OUT * 192; i += 256) {
    int co = i / 192;
    int r = i - co * 192;
    wl[co * PW + r] = f2bf(w[i]);
  }
  if (t < C_OUT) bias_s[t] = bias[t];

  // ---- x tile -> LDS bf16, layout xs[ci][j], j in [0, NT+2)
  {
    const int tj = t & 63;
    const int tc = t >> 6;
    const float* xb = x + (size_t)b * C_IN * L_IN + l0;
    for (int ci = tc; ci < C_IN; ci += 4) {
      const float* xr = xb + (size_t)ci * L_IN;
#pragma unroll
      for (int j0 = 0; j0 < 320; j0 += 64) {
        int j = j0 + tj;
        if (j < NT + 2) {
          float v = 0.0f;
          if (l0 + j < L_IN) v = xr[j];   // only last tile can go OOB
          xs[ci * PX + j] = f2bf(v);
        }
      }
    }
  }
  __syncthreads();

  // ---- MFMA main loop: wave wv owns n in [wv*64, wv*64+64), all 64 co
  const int lane = t & 63;
  const int wv = t >> 6;
  const int half = lane >> 5;   // k-half within fragment
  const int ln = lane & 31;
  const int n0 = wv * 64 + ln;  // nt=0 column for this lane
  const int kh = half * 8;

  f32x16 acc00 = {}, acc01 = {}, acc10 = {}, acc11 = {};

#pragma unroll
  for (int s = 0; s < 12; ++s) {
    // A fragments: 8 contiguous bf16 per lane -> ds_read_b128
    bf16x8 a0 = *(const bf16x8*)&wl[ln * PW + s * 16 + kh];
    bf16x8 a1 = *(const bf16x8*)&wl[(32 + ln) * PW + s * 16 + kh];
    // B fragments: gather 8 bf16 via implicit im2col
    ushort8 b0u, b1u;
#pragma unroll
    for (int jj = 0; jj < 8; ++jj) {
      unsigned k = (unsigned)(s * 16 + kh + jj);
      unsigned ci = (k * 0xAAABu) >> 17;  // k/3 (exact for k<2^16)
      unsigned kk = k - ci * 3u;
      int base = (int)(ci * PX + kk) + n0;
      b0u[jj] = xs[base];
      b1u[jj] = xs[base + 32];
    }
    bf16x8 b0 = __builtin_bit_cast(bf16x8, b0u);
    bf16x8 b1 = __builtin_bit_cast(bf16x8, b1u);
    acc00 = __builtin_amdgcn_mfma_f32_32x32x16_bf16(a0, b0, acc00, 0, 0, 0);
    acc01 = __builtin_amdgcn_mfma_f32_32x32x16_bf16(a0, b1, acc01, 0, 0, 0);
    acc10 = __builtin_amdgcn_mfma_f32_32x32x16_bf16(a1, b0, acc10, 0, 0, 0);
    acc11 = __builtin_amdgcn_mfma_f32_32x32x16_bf16(a1, b1, acc11, 0, 0, 0);
  }

  // ---- epilogue: C/D layout col = lane&31, row = (r&3) + 8*(r>>2) + 4*half
  const int l_base = l0 + wv * 64 + ln;
  const bool full = (l0 + NT <= L_OUT);  // only last tile needs guards
  if (full) {
#pragma unroll
    for (int mt = 0; mt < 2; ++mt) {
#pragma unroll
      for (int r = 0; r < 16; ++r) {
        int co = mt * 32 + 4 * half + (r & 3) + 8 * (r >> 2);
        float bv = bias_s[co];
        size_t row = ((size_t)b * C_OUT + co) * (size_t)L_OUT;
        float v0 = (mt == 0 ? acc00[r] : acc10[r]) + bv;
        float v1 = (mt == 0 ? acc01[r] : acc11[r]) + bv;
        out[row + l_base] = v0;
        out[row + l_base + 32] = v1;
      }
    }
  } else {
#pragma unroll
    for (int mt = 0; mt < 2; ++mt) {
#pragma unroll
      for (int r = 0; r < 16; ++r) {
        int co = mt * 32 + 4 * half + (r & 3) + 8 * (r >> 2);
        float bv = bias_s[co];
        size_t row = ((size_t)b * C_OUT + co) * (size_t)L_OUT;
        float v0 = (mt == 0 ? acc00[r] : acc10[r]) + bv;
        float v1 = (mt == 0 ? acc01[r] : acc11[r]) + bv;
        if (l_base < L_OUT) out[row + l_base] = v0;
        if (l_base + 32 < L_OUT) out[row + l_base + 32] = v1;
      }
    }
  }
}

extern "C" void kernel_launch(void* const* d_in, const int* in_sizes, int n_in,
                              void* d_out, int out_size, void* d_ws, size_t ws_size,
                              hipStream_t stream) {
  const float* x = (const float*)d_in[0];
  const float* w = (const float*)d_in[1];
  const float* bias = (const float*)d_in[2];
  float* out = (float*)d_out;
  // 32 batches * 64 l-tiles of 256 columns
  conv1d_mfma<<<dim3(32 * 64), dim3(256), 0, stream>>>(x, w, bias, out);
}

// Round 2
// 283.905 us; speedup vs baseline: 1.0738x; 1.0738x over previous
//
#include <hip/hip_runtime.h>

// Conv1d: x (32, 64, 16384) f32, w (64, 64, 3) f32, bias (64) f32
// -> out (32, 64, 16382) f32, VALID, stride 1.
// GEMM view: out[co][n] = sum_kappa A[co][kappa] * B[kappa][n] + bias[co]
//   kappa = kk*64 + ci  (kk-major!) so each 8-elem B fragment has uniform kk
//   and consecutive ci -> 8 coalesced global loads at stride L_IN, clamp is
//   one min per fragment. No x LDS tile at all; L1/L2 serve the kk-reuse.
//   A[co][kk*64+ci] = w[co][ci][kk]  (transposed into LDS at stage time)

typedef __bf16 bf16x8 __attribute__((ext_vector_type(8)));
typedef unsigned short ushort8 __attribute__((ext_vector_type(8)));
typedef float f32x16 __attribute__((ext_vector_type(16)));

#define C_IN 64
#define C_OUT 64
#define L_IN 16384
#define L_OUT 16382
#define NT 256          // n-columns per block
#define PW 200          // wl row pitch (elems); keeps 16B align, no conflicts (measured 0)

__device__ __forceinline__ unsigned short f2bf(float f) {
  unsigned u = __builtin_bit_cast(unsigned, f);
  return (unsigned short)((u + 0x7FFFu + ((u >> 16) & 1u)) >> 16);  // RNE
}

__global__ __launch_bounds__(256, 4) void conv1d_mfma(
    const float* __restrict__ x, const float* __restrict__ w,
    const float* __restrict__ bias, float* __restrict__ out) {
  __shared__ __align__(16) unsigned short wl[C_OUT * PW];  // 25600 B
  __shared__ float bias_s[C_OUT];

  const int t = threadIdx.x;
  const int bx = blockIdx.x;
  const int b = bx >> 6;        // batch
  const int tile = bx & 63;     // l-tile
  const int l0 = tile * NT;

  // ---- weights -> LDS bf16, layout wl[co][kk*64 + ci] (kappa-order)
  for (int i = t; i < C_OUT * 192; i += 256) {
    int co = i / 192;
    int r = i - co * 192;
    int ci = r / 3;
    int kk = r - ci * 3;
    wl[co * PW + kk * 64 + ci] = f2bf(w[i]);
  }
  if (t < C_OUT) bias_s[t] = bias[t];
  __syncthreads();

  // ---- MFMA main loop: wave wv owns n in [wv*64, wv*64+64), all 64 co
  const int lane = t & 63;
  const int wv = t >> 6;
  const int half = lane >> 5;   // k-half within fragment
  const int ln = lane & 31;
  const int kh = half * 8;
  const int n0 = wv * 64 + ln;
  const int l_a = l0 + n0;      // column for b0 fragments

  const float* xb = x + (size_t)b * (C_IN * L_IN);

  f32x16 acc00 = {}, acc01 = {}, acc10 = {}, acc11 = {};

#pragma unroll
  for (int s = 0; s < 12; ++s) {
    // A fragments: 8 contiguous bf16 per lane -> ds_read_b128
    bf16x8 a0 = *(const bf16x8*)&wl[ln * PW + s * 16 + kh];
    bf16x8 a1 = *(const bf16x8*)&wl[(32 + ln) * PW + s * 16 + kh];

    // B fragments: kappa = s*16 + kh + jj -> kk uniform, ci consecutive
    int tt = s * 16 + kh;
    int kk = tt >> 6;           // uniform over the 8-elem fragment
    int ci0 = tt & 63;
    int p0 = min(l_a + kk, L_IN - 1);        // clamp once per fragment;
    int p1 = min(l_a + 32 + kk, L_IN - 1);   // clamped lanes feed unstored cols
    int base = ci0 * L_IN;
    ushort8 b0u, b1u;
#pragma unroll
    for (int jj = 0; jj < 8; ++jj) {
      b0u[jj] = f2bf(xb[base + jj * L_IN + p0]);
      b1u[jj] = f2bf(xb[base + jj * L_IN + p1]);
    }
    bf16x8 b0 = __builtin_bit_cast(bf16x8, b0u);
    bf16x8 b1 = __builtin_bit_cast(bf16x8, b1u);
    acc00 = __builtin_amdgcn_mfma_f32_32x32x16_bf16(a0, b0, acc00, 0, 0, 0);
    acc01 = __builtin_amdgcn_mfma_f32_32x32x16_bf16(a0, b1, acc01, 0, 0, 0);
    acc10 = __builtin_amdgcn_mfma_f32_32x32x16_bf16(a1, b0, acc10, 0, 0, 0);
    acc11 = __builtin_amdgcn_mfma_f32_32x32x16_bf16(a1, b1, acc11, 0, 0, 0);
  }

  // ---- epilogue: C/D layout col = lane&31, row = (r&3) + 8*(r>>2) + 4*half
  const int l_base = l0 + wv * 64 + ln;
  const bool full = (l0 + NT <= L_OUT);  // only last tile needs guards
  if (full) {
#pragma unroll
    for (int mt = 0; mt < 2; ++mt) {
#pragma unroll
      for (int r = 0; r < 16; ++r) {
        int co = mt * 32 + 4 * half + (r & 3) + 8 * (r >> 2);
        float bv = bias_s[co];
        size_t row = ((size_t)b * C_OUT + co) * (size_t)L_OUT;
        float v0 = (mt == 0 ? acc00[r] : acc10[r]) + bv;
        float v1 = (mt == 0 ? acc01[r] : acc11[r]) + bv;
        out[row + l_base] = v0;
        out[row + l_base + 32] = v1;
      }
    }
  } else {
#pragma unroll
    for (int mt = 0; mt < 2; ++mt) {
#pragma unroll
      for (int r = 0; r < 16; ++r) {
        int co = mt * 32 + 4 * half + (r & 3) + 8 * (r >> 2);
        float bv = bias_s[co];
        size_t row = ((size_t)b * C_OUT + co) * (size_t)L_OUT;
        float v0 = (mt == 0 ? acc00[r] : acc10[r]) + bv;
        float v1 = (mt == 0 ? acc01[r] : acc11[r]) + bv;
        if (l_base < L_OUT) out[row + l_base] = v0;
        if (l_base + 32 < L_OUT) out[row + l_base + 32] = v1;
      }
    }
  }
}

extern "C" void kernel_launch(void* const* d_in, const int* in_sizes, int n_in,
                              void* d_out, int out_size, void* d_ws, size_t ws_size,
                              hipStream_t stream) {
  const float* x = (const float*)d_in[0];
  const float* w = (const float*)d_in[1];
  const float* bias = (const float*)d_in[2];
  float* out = (float*)d_out;
  // 32 batches * 64 l-tiles of 256 columns
  conv1d_mfma<<<dim3(32 * 64), dim3(256), 0, stream>>>(x, w, bias, out);
}